// Round 6
// baseline (2541.143 us; speedup 1.0000x reference)
//
#include <hip/hip_runtime.h>
#include <math.h>

#define NN 1024
#define NM (NN*NN)
#define NB 64
#define NBLK 16
#define NW 1152
#define BIG 4096

#define OFF_FVAR  ((size_t)4096)
#define OFF_NOISE ((size_t)(4096 + 16777216))
#define OFF_M4    ((size_t)(4096 + 2*16777216))

struct GPParams {
  float tk[16];   // task_K[a*4+b]
  float E[16];    // E[a*4+i]
  float G[16];    // G[a*4+i]
  float lam[4];
};

// ---------------- small setup: task_K, 4x4 Jacobi eigendecomp ----------------
__global__ void k_prep(const float* __restrict__ logn, const float* __restrict__ cf,
                       const float* __restrict__ logv, GPParams* __restrict__ P)
{
  if (threadIdx.x != 0 || blockIdx.x != 0) return;
  double tk[4][4], Dn[4], T[4][4], U[4][4];
  for (int a=0;a<4;a++) for (int b=0;b<4;b++){
    double s = 0.0;
    for (int r=0;r<2;r++) s += (double)cf[a*2+r]*(double)cf[b*2+r];
    if (a==b) s += exp((double)logv[a]);
    tk[a][b] = s;
  }
  for (int a=0;a<4;a++) Dn[a] = exp((double)logn[a]);
  for (int a=0;a<4;a++) for (int b=0;b<4;b++)
    T[a][b] = tk[a][b]/sqrt(Dn[a]*Dn[b]);
  for (int a=0;a<4;a++) for (int b=0;b<4;b++) U[a][b] = (a==b)?1.0:0.0;
  for (int sweep=0; sweep<40; sweep++){
    for (int p=0;p<3;p++) for (int q=p+1;q<4;q++){
      double apq = T[p][q];
      if (fabs(apq) < 1e-300) continue;
      double tau = (T[q][q]-T[p][p])/(2.0*apq);
      double t = (tau >= 0.0) ? 1.0/(tau + sqrt(1.0+tau*tau))
                              : 1.0/(tau - sqrt(1.0+tau*tau));
      double c = 1.0/sqrt(1.0+t*t), s = t*c;
      for (int k=0;k<4;k++){ double akp=T[k][p], akq=T[k][q];
        T[k][p]=c*akp - s*akq; T[k][q]=s*akp + c*akq; }
      for (int k=0;k<4;k++){ double apk=T[p][k], aqk=T[q][k];
        T[p][k]=c*apk - s*aqk; T[q][k]=s*apk + c*aqk; }
      for (int k=0;k<4;k++){ double ukp=U[k][p], ukq=U[k][q];
        U[k][p]=c*ukp - s*ukq; U[k][q]=s*ukp + c*ukq; }
    }
  }
  double E[4][4], G[4][4];
  for (int a=0;a<4;a++) for (int i=0;i<4;i++) E[a][i] = U[a][i]/sqrt(Dn[a]);
  for (int a=0;a<4;a++) for (int i=0;i<4;i++){
    double s=0; for (int b=0;b<4;b++) s += tk[a][b]*E[b][i];
    G[a][i]=s;
  }
  for (int a=0;a<4;a++) for (int b=0;b<4;b++){
    P->tk[a*4+b] = (float)tk[a][b];
    P->E [a*4+b] = (float)E[a][b];
    P->G [a*4+b] = (float)G[a][b];
  }
  for (int i=0;i<4;i++){
    double l = T[i][i];
    P->lam[i] = (float)(l > 0.0 ? l : 0.0);
  }
}

// ---------------- RBF kernel matrix ----------------
__global__ void k_rbf(const float* __restrict__ X1, const float* __restrict__ X2,
                      const float* __restrict__ logls, float* __restrict__ out)
{
  __shared__ float x1s[16][8];
  __shared__ float x2s[16][8];
  int tx = threadIdx.x, ty = threadIdx.y;
  int tid = ty*16 + tx;
  if (tid < 128){
    int r = tid>>3, d = tid&7;
    x1s[r][d] = X1[((size_t)blockIdx.y*16 + r)*8 + d];
  } else {
    int t2 = tid-128, r = t2>>3, d = t2&7;
    x2s[r][d] = X2[((size_t)blockIdx.x*16 + r)*8 + d];
  }
  __syncthreads();
  float ls2 = expf(2.0f*logls[0]);
  float d2 = 0.f;
  #pragma unroll
  for (int d=0; d<8; d++){ float df = x1s[ty][d]-x2s[tx][d]; d2 += df*df; }
  int i = blockIdx.y*16+ty, j = blockIdx.x*16+tx;
  out[(size_t)i*NN + j] = expf(-0.5f*d2/ls2);
}

// ---------------- rbf(X,X) fused with M_z = lam_z * C + I ----------------
__global__ void k_rbfM(const float* __restrict__ X1, const float* __restrict__ logls,
                       const GPParams* __restrict__ P, float* __restrict__ M)
{
  __shared__ float x1s[16][8];
  __shared__ float x2s[16][8];
  int tx = threadIdx.x, ty = threadIdx.y;
  int tid = ty*16 + tx;
  if (tid < 128){
    int r = tid>>3, d = tid&7;
    x1s[r][d] = X1[((size_t)blockIdx.y*16 + r)*8 + d];
  } else {
    int t2 = tid-128, r = t2>>3, d = t2&7;
    x2s[r][d] = X1[((size_t)blockIdx.x*16 + r)*8 + d];
  }
  __syncthreads();
  float ls2 = expf(2.0f*logls[0]);
  float d2 = 0.f;
  #pragma unroll
  for (int d=0; d<8; d++){ float df = x1s[ty][d]-x2s[tx][d]; d2 += df*df; }
  int i = blockIdx.y*16+ty, j = blockIdx.x*16+tx;
  float v = expf(-0.5f*d2/ls2);
  float diag = (i==j) ? 1.f : 0.f;
  size_t idx = (size_t)i*NN + j;
  #pragma unroll
  for (int z=0;z<4;z++)
    M[(size_t)z*NM + idx] = P->lam[z]*v + diag;
}

// ---------------- u_i = sum_a E[a][i] * Y[:,a] ----------------
__global__ void k_uvec(const float* __restrict__ Y, const GPParams* __restrict__ P,
                       float* __restrict__ u)
{
  int n = blockIdx.x*256 + threadIdx.x;
  float y0 = Y[n*4+0], y1 = Y[n*4+1], y2 = Y[n*4+2], y3 = Y[n*4+3];
  #pragma unroll
  for (int i=0;i<4;i++)
    u[i*NN + n] = P->E[0*4+i]*y0 + P->E[1*4+i]*y1 + P->E[2*4+i]*y2 + P->E[3*4+i]*y3;
}

// ---------------- 4x4-microtile 64-K GEMMs from LDS ----------------
// acc += A[r][p] * B[p][c]
__device__ __forceinline__ void gemm64(const float* __restrict__ A, const float* __restrict__ B,
                                       float acc[4][4], int r0, int c0, bool sub)
{
  for (int p=0;p<64;p++){
    float ar[4], bc[4];
    #pragma unroll
    for (int ii=0;ii<4;ii++) ar[ii]=A[(r0+ii)*65+p];
    #pragma unroll
    for (int jj=0;jj<4;jj++) bc[jj]=B[p*65+c0+jj];
    if (sub){
      #pragma unroll
      for (int ii=0;ii<4;ii++)
        #pragma unroll
        for (int jj=0;jj<4;jj++) acc[ii][jj] -= ar[ii]*bc[jj];
    } else {
      #pragma unroll
      for (int ii=0;ii<4;ii++)
        #pragma unroll
        for (int jj=0;jj<4;jj++) acc[ii][jj] += ar[ii]*bc[jj];
    }
  }
}
// acc += A[r][p] * B[c][p]   (B accessed by row => A * B^T)
__device__ __forceinline__ void gemm64T(const float* __restrict__ A, const float* __restrict__ B,
                                        float acc[4][4], int r0, int c0)
{
  for (int p=0;p<64;p++){
    float ar[4], bc[4];
    #pragma unroll
    for (int ii=0;ii<4;ii++) ar[ii]=A[(r0+ii)*65+p];
    #pragma unroll
    for (int jj=0;jj<4;jj++) bc[jj]=B[(c0+jj)*65+p];
    #pragma unroll
    for (int ii=0;ii<4;ii++)
      #pragma unroll
      for (int jj=0;jj<4;jj++) acc[ii][jj] += ar[ii]*bc[jj];
  }
}

// ---------------- Cholesky diag k: factor 64x64 + 2-level inversion + G = Linv^T Linv ----------------
__global__ __launch_bounds__(256) void k_potf2(float* __restrict__ M, float* __restrict__ Linv,
                                               float* __restrict__ Gbuf, int k)
{
  int z = blockIdx.x, tid = threadIdx.x;
  __shared__ float a[64*65];    // unscaled working copy -> later full Linv
  __shared__ float lo[64*65];   // scaled L output
  __shared__ float ai[32*33];
  __shared__ float bb[32*33];
  __shared__ float t1[32*33];
  float* Mz = M + (size_t)z*NM;
  int base = k*NB;
  for (int idx=tid; idx<4096; idx+=256){
    int r=idx>>6, c=idx&63;
    a[r*65+c] = Mz[(size_t)(base+r)*NN + base + c];
  }
  int r = tid & 63, q = tid >> 6;
  for (int j=0;j<64;j++){
    __syncthreads();
    float d = a[j*65+j];
    float invd = 1.f/d;
    float rs = rsqrtf(d);
    if (q==0){
      if (r == j) lo[j*65+j] = sqrtf(d);
      else if (r > j) lo[r*65+j] = a[r*65+j]*rs;
      else lo[r*65+j] = 0.f;
    }
    if (r > j){
      float lrj = a[r*65+j]*invd;
      for (int c=j+1+q; c<=r; c+=4)
        a[r*65+c] -= lrj * a[c*65+j];
    }
  }
  __syncthreads();
  if (tid < 32){
    int c = tid;
    for (int rr=0;rr<c;rr++) ai[rr*33+c]=0.f;
    for (int rr=c;rr<32;rr++){
      float s = (rr==c)?1.f:0.f;
      for (int j=c;j<rr;j++) s -= lo[rr*65+j]*ai[j*33+c];
      ai[rr*33+c] = s / lo[rr*65+rr];
    }
  } else if (tid < 64){
    int c = tid-32;
    for (int rr=0;rr<c;rr++) bb[rr*33+c]=0.f;
    for (int rr=c;rr<32;rr++){
      float s=(rr==c)?1.f:0.f;
      for (int j=c;j<rr;j++) s -= lo[(32+rr)*65+(32+j)]*bb[j*33+c];
      bb[rr*33+c] = s / lo[(32+rr)*65+(32+rr)];
    }
  }
  __syncthreads();
  for (int idx=tid; idx<1024; idx+=256){
    int rr=idx>>5, c=idx&31;
    float s=0.f;
    for (int j=0;j<32;j++) s += lo[(32+rr)*65+j]*ai[j*33+c];
    t1[rr*33+c]=s;
  }
  __syncthreads();
  float* Lg = Linv + ((size_t)z*NBLK + k)*(NB*NB);
  float* Td = Mz + (size_t)base*NN + base;
  for (int idx=tid; idx<1024; idx+=256){
    int rr=idx>>5, c=idx&31;
    float s=0.f;
    for (int j=0;j<32;j++) s += bb[rr*33+j]*t1[j*33+c];
    float q21 = -s, q11 = ai[rr*33+c], q22 = bb[rr*33+c];
    Lg[(32+rr)*64 + c]      = q21;
    Lg[rr*64 + (32+c)]      = 0.f;
    Lg[rr*64 + c]           = q11;
    Lg[(32+rr)*64 + (32+c)] = q22;
    Td[(size_t)(32+rr)*NN + c]      = q21;
    Td[(size_t)rr*NN + (32+c)]      = 0.f;
    Td[(size_t)rr*NN + c]           = q11;
    Td[(size_t)(32+rr)*NN + (32+c)] = q22;
    // assemble full Linv into a[]
    a[(32+rr)*65 + c]      = q21;
    a[rr*65 + (32+c)]      = 0.f;
    a[rr*65 + c]           = q11;
    a[(32+rr)*65 + (32+c)] = q22;
  }
  __syncthreads();
  // G = Linv^T Linv
  {
    int r0=(tid>>4)*4, c0=(tid&15)*4;
    float g[4][4]={};
    for (int p=0;p<64;p++){
      float ar[4], bc[4];
      #pragma unroll
      for (int ii=0;ii<4;ii++) ar[ii]=a[p*65+r0+ii];
      #pragma unroll
      for (int jj=0;jj<4;jj++) bc[jj]=a[p*65+c0+jj];
      #pragma unroll
      for (int ii=0;ii<4;ii++)
        #pragma unroll
        for (int jj=0;jj<4;jj++) g[ii][jj]+=ar[ii]*bc[jj];
    }
    float* Gg = Gbuf + ((size_t)z*NBLK + k)*4096;
    #pragma unroll
    for (int ii=0;ii<4;ii++)
      *(float4*)&Gg[(r0+ii)*64 + c0] = make_float4(g[ii][0],g[ii][1],g[ii][2],g[ii][3]);
  }
}

// ------- fused chol step k (G-based): tiles do M[bi][bj] -= P_bi * G * P_bj^T;
// ------- first-column tiles also archive scaled panel; the (k+1,k+1) block factors.
__global__ __launch_bounds__(256) void k_csf(float* __restrict__ M, float* __restrict__ Linv,
                                             float* __restrict__ Gbuf, float* __restrict__ Lbuf, int k)
{
  int z = blockIdx.z;
  int tt = blockIdx.x, i2 = 0;
  while (tt >= i2+1){ tt -= (i2+1); i2++; }
  int bi = k+1+i2, bj = k+1+tt;
  bool fblk = (i2==0);               // bi==bj==k+1
  __shared__ float pa[64*65];
  __shared__ float pb[64*65];
  __shared__ float li[64*65];
  float* Mz = M + (size_t)z*NM;
  float* Lb = Lbuf + (size_t)z*NM;
  int tid = threadIdx.x;
  int ty = tid>>4, tx = tid&15;
  int r0 = ty*4, c0 = tx*4;

  if (fblk){
    // ---- diagonal factor block ----
    const float* Lg = Linv + ((size_t)z*NBLK + k)*(NB*NB);
    for (int idx=tid; idx<4096; idx+=256){
      int r=idx>>6, c=idx&63;
      li[r*65+c] = Lg[idx];
      pa[r*65+c] = Mz[(size_t)(bi*64+r)*NN + k*64 + c];   // raw panel
      pb[r*65+c] = Mz[(size_t)(bi*64+r)*NN + bi*64 + c];  // raw diag
    }
    __syncthreads();
    float sc[4][4]={};
    gemm64T(pa, li, sc, r0, c0);         // scaled = P * Linv^T
    #pragma unroll
    for (int ii=0;ii<4;ii++)
      *(float4*)&Lb[(size_t)(bi*64+r0+ii)*NN + k*64+c0] =
        make_float4(sc[ii][0],sc[ii][1],sc[ii][2],sc[ii][3]);
    __syncthreads();
    #pragma unroll
    for (int ii=0;ii<4;ii++)
      #pragma unroll
      for (int jj=0;jj<4;jj++) pa[(r0+ii)*65+c0+jj] = sc[ii][jj];
    __syncthreads();
    float upd[4][4]={};
    gemm64T(pa, pa, upd, r0, c0);        // scaled * scaled^T
    #pragma unroll
    for (int ii=0;ii<4;ii++)
      #pragma unroll
      for (int jj=0;jj<4;jj++) pb[(r0+ii)*65+c0+jj] -= upd[ii][jj];
    // factor pb (unscaled working), write scaled L into li
    int r = tid & 63, q = tid >> 6;
    for (int j=0;j<64;j++){
      __syncthreads();
      float d = pb[j*65+j];
      float invd = 1.f/d;
      float rs = rsqrtf(d);
      if (q==0){
        if (r == j) li[j*65+j] = sqrtf(d);
        else if (r > j) li[r*65+j] = pb[r*65+j]*rs;
        else li[r*65+j] = 0.f;
      }
      if (r > j){
        float lrj = pb[r*65+j]*invd;
        for (int c=j+1+q; c<=r; c+=4)
          pb[r*65+c] -= lrj * pb[c*65+j];
      }
    }
    __syncthreads();
    // 2-level inversion of li; scratch in pa region (dead)
    float* ai = pa;          // 32*33
    float* bbv = pa + 1056;  // 32*33
    float* t1 = pa + 2112;   // 32*33
    if (tid < 32){
      int c = tid;
      for (int rr=0;rr<c;rr++) ai[rr*33+c]=0.f;
      for (int rr=c;rr<32;rr++){
        float s = (rr==c)?1.f:0.f;
        for (int j=c;j<rr;j++) s -= li[rr*65+j]*ai[j*33+c];
        ai[rr*33+c] = s / li[rr*65+rr];
      }
    } else if (tid < 64){
      int c = tid-32;
      for (int rr=0;rr<c;rr++) bbv[rr*33+c]=0.f;
      for (int rr=c;rr<32;rr++){
        float s=(rr==c)?1.f:0.f;
        for (int j=c;j<rr;j++) s -= li[(32+rr)*65+(32+j)]*bbv[j*33+c];
        bbv[rr*33+c] = s / li[(32+rr)*65+(32+rr)];
      }
    }
    __syncthreads();
    for (int idx=tid; idx<1024; idx+=256){
      int rr=idx>>5, c=idx&31;
      float s=0.f;
      for (int j=0;j<32;j++) s += li[(32+rr)*65+j]*ai[j*33+c];
      t1[rr*33+c]=s;
    }
    __syncthreads();
    float* Lg2 = Linv + ((size_t)z*NBLK + (k+1))*(NB*NB);
    float* Td  = Mz + (size_t)(bi*64)*NN + bi*64;
    for (int idx=tid; idx<1024; idx+=256){
      int rr=idx>>5, c=idx&31;
      float s=0.f;
      for (int j=0;j<32;j++) s += bbv[rr*33+j]*t1[j*33+c];
      float q21 = -s, q11 = ai[rr*33+c], q22 = bbv[rr*33+c];
      Lg2[(32+rr)*64 + c]      = q21;
      Lg2[rr*64 + (32+c)]      = 0.f;
      Lg2[rr*64 + c]           = q11;
      Lg2[(32+rr)*64 + (32+c)] = q22;
      Td[(size_t)(32+rr)*NN + c]      = q21;
      Td[(size_t)rr*NN + (32+c)]      = 0.f;
      Td[(size_t)rr*NN + c]           = q11;
      Td[(size_t)(32+rr)*NN + (32+c)] = q22;
      // assemble full Linv into pb[] (dead)
      pb[(32+rr)*65 + c]      = q21;
      pb[rr*65 + (32+c)]      = 0.f;
      pb[rr*65 + c]           = q11;
      pb[(32+rr)*65 + (32+c)] = q22;
    }
    __syncthreads();
    // G_{k+1} = Linv^T Linv
    {
      float g[4][4]={};
      for (int p=0;p<64;p++){
        float ar[4], bc[4];
        #pragma unroll
        for (int ii=0;ii<4;ii++) ar[ii]=pb[p*65+r0+ii];
        #pragma unroll
        for (int jj=0;jj<4;jj++) bc[jj]=pb[p*65+c0+jj];
        #pragma unroll
        for (int ii=0;ii<4;ii++)
          #pragma unroll
          for (int jj=0;jj<4;jj++) g[ii][jj]+=ar[ii]*bc[jj];
      }
      float* Gg = Gbuf + ((size_t)z*NBLK + (k+1))*4096;
      #pragma unroll
      for (int ii=0;ii<4;ii++)
        *(float4*)&Gg[(r0+ii)*64 + c0] = make_float4(g[ii][0],g[ii][1],g[ii][2],g[ii][3]);
    }
    return;
  }

  // ---- general tile: M[bi][bj] -= P_bi * G * P_bj^T ----
  const float* Gg = Gbuf + ((size_t)z*NBLK + k)*4096;
  for (int idx=tid; idx<4096; idx+=256){
    int r=idx>>6, c=idx&63;
    li[r*65+c] = Gg[idx];
    pa[r*65+c] = Mz[(size_t)(bi*64+r)*NN + k*64 + c];
    pb[r*65+c] = Mz[(size_t)(bj*64+r)*NN + k*64 + c];
  }
  __syncthreads();
  float t[4][4]={};
  gemm64(pa, li, t, r0, c0, false);      // t = P_bi * G
  __syncthreads();
  #pragma unroll
  for (int ii=0;ii<4;ii++)
    #pragma unroll
    for (int jj=0;jj<4;jj++) li[(r0+ii)*65+c0+jj] = t[ii][jj];
  __syncthreads();
  float upd[4][4]={};
  gemm64T(li, pb, upd, r0, c0);          // t * P_bj^T
  #pragma unroll
  for (int ii=0;ii<4;ii++){
    float4* ptr = (float4*)&Mz[(size_t)(bi*64+r0+ii)*NN + bj*64+c0];
    float4 v = *ptr;
    v.x-=upd[ii][0]; v.y-=upd[ii][1]; v.z-=upd[ii][2]; v.w-=upd[ii][3];
    *ptr = v;
  }
  if (bj == k+1){
    // archive scaled panel: P_bi * Linv^T
    __syncthreads();
    const float* Lg = Linv + ((size_t)z*NBLK + k)*(NB*NB);
    for (int idx=tid; idx<4096; idx+=256){
      int r=idx>>6, c=idx&63;
      pb[r*65+c] = Lg[idx];
    }
    __syncthreads();
    float sc[4][4]={};
    gemm64T(pa, pb, sc, r0, c0);
    #pragma unroll
    for (int ii=0;ii<4;ii++)
      *(float4*)&Lb[(size_t)(bi*64+r0+ii)*NN + k*64+c0] =
        make_float4(sc[ii][0],sc[ii][1],sc[ii][2],sc[ii][3]);
  }
}

// ---------------- doubling step 1 (fused): Tinv(2p+1,2p) = -Binv * L21 * Ainv ----------------
__global__ __launch_bounds__(256) void k_dbl1(const float* __restrict__ Lbuf,
                                              const float* __restrict__ Linv,
                                              float* __restrict__ Tinv)
{
  int pair = blockIdx.x, z = blockIdx.y, tid = threadIdx.x;
  int b0 = 2*pair, b1 = 2*pair+1;
  __shared__ float l21[64*65];
  __shared__ float ai[64*65];
  __shared__ float tt[64*65];
  const float* Lb = Lbuf + (size_t)z*NM;
  const float* La = Linv + ((size_t)z*NBLK + b0)*(NB*NB);
  const float* Lc = Linv + ((size_t)z*NBLK + b1)*(NB*NB);
  for (int idx=tid; idx<4096; idx+=256){
    int r=idx>>6, c=idx&63;
    l21[r*65+c] = Lb[(size_t)(b1*64+r)*NN + b0*64 + c];
    ai[r*65+c]  = La[idx];
  }
  __syncthreads();
  int ty=tid>>4, tx=tid&15, r0=ty*4, c0=tx*4;
  float acc[4][4]={};
  gemm64(l21, ai, acc, r0, c0, false);
  __syncthreads();
  #pragma unroll
  for (int ii=0;ii<4;ii++)
    #pragma unroll
    for (int jj=0;jj<4;jj++) tt[(r0+ii)*65 + c0+jj] = acc[ii][jj];
  for (int idx=tid; idx<4096; idx+=256){
    int r=idx>>6, c=idx&63;
    ai[r*65+c] = Lc[idx];
  }
  __syncthreads();
  float fin[4][4]={};
  gemm64(ai, tt, fin, r0, c0, false);
  float* Tz = Tinv + (size_t)z*NM;
  #pragma unroll
  for (int ii=0;ii<4;ii++){
    float4 v = make_float4(-fin[ii][0],-fin[ii][1],-fin[ii][2],-fin[ii][3]);
    *(float4*)&Tz[(size_t)(b1*64+r0+ii)*NN + b0*64+c0] = v;
  }
}

// ---------------- doubling: t = L21 * Tinv11 ----------------
__global__ __launch_bounds__(256) void k_dblT(const float* __restrict__ Lbuf,
                                              const float* __restrict__ Tinv,
                                              float* __restrict__ tb, int g64)
{
  int z = blockIdx.y, tid = threadIdx.x;
  int tpp = g64*g64;
  int pair = blockIdx.x / tpp;
  int tt2 = blockIdx.x % tpp;
  int ti = tt2 / g64, tj = tt2 % g64;
  int b0 = 2*pair*g64, b1 = b0 + g64;
  const float* Lb = Lbuf + (size_t)z*NM;
  const float* Tz = Tinv + (size_t)z*NM;
  __shared__ float lt[64*65];
  __shared__ float rt[64*65];
  int ty=tid>>4, tx=tid&15, r0=ty*4, c0=tx*4;
  float acc[4][4]={};
  for (int kb=tj; kb<g64; kb++){
    for (int idx=tid; idx<4096; idx+=256){
      int r=idx>>6, c=idx&63;
      lt[r*65+c] = Lb[(size_t)((b1+ti)*64+r)*NN + (b0+kb)*64 + c];
      rt[r*65+c] = Tz[(size_t)((b0+kb)*64+r)*NN + (b0+tj)*64 + c];
    }
    __syncthreads();
    gemm64(lt, rt, acc, r0, c0, false);
    __syncthreads();
  }
  int g = g64*64;
  float* tz = tb + (size_t)z*262144 + (size_t)pair*g*g;
  #pragma unroll
  for (int ii=0;ii<4;ii++){
    float4 v = make_float4(acc[ii][0],acc[ii][1],acc[ii][2],acc[ii][3]);
    *(float4*)&tz[(size_t)(ti*64+r0+ii)*g + tj*64+c0] = v;
  }
}

// ---------------- doubling: Tinv21 = -Tinv22 * t ----------------
__global__ __launch_bounds__(256) void k_dblC(const float* __restrict__ tb,
                                              float* __restrict__ Tinv, int g64)
{
  int z = blockIdx.y, tid = threadIdx.x;
  int tpp = g64*g64;
  int pair = blockIdx.x / tpp;
  int tt2 = blockIdx.x % tpp;
  int ti = tt2 / g64, tj = tt2 % g64;
  int b0 = 2*pair*g64, b1 = b0 + g64;
  float* Tz = Tinv + (size_t)z*NM;
  int g = g64*64;
  const float* tz = tb + (size_t)z*262144 + (size_t)pair*g*g;
  __shared__ float lt[64*65];
  __shared__ float rt[64*65];
  int ty=tid>>4, tx=tid&15, r0=ty*4, c0=tx*4;
  float acc[4][4]={};
  for (int kb=0; kb<=ti; kb++){
    for (int idx=tid; idx<4096; idx+=256){
      int r=idx>>6, c=idx&63;
      lt[r*65+c] = Tz[(size_t)((b1+ti)*64+r)*NN + (b1+kb)*64 + c];
      rt[r*65+c] = tz[(size_t)(kb*64+r)*g + tj*64 + c];
    }
    __syncthreads();
    gemm64(lt, rt, acc, r0, c0, false);
    __syncthreads();
  }
  #pragma unroll
  for (int ii=0;ii<4;ii++){
    float4 v = make_float4(-acc[ii][0],-acc[ii][1],-acc[ii][2],-acc[ii][3]);
    *(float4*)&Tz[(size_t)((b1+ti)*64+r0+ii)*NN + b0*64+tj*64+c0] = v;
  }
}

// ---------------- W = Tinv * [R | u] : 64x128 tiles, 4x8 micro, reg prefetch ----------------
__global__ __launch_bounds__(256) void k_wgemm(const float* __restrict__ Tinv,
                                               const float* __restrict__ R,
                                               const float* __restrict__ u,
                                               float* __restrict__ W)
{
  int ct = blockIdx.x;      // 0..8 (8 = u/pad tile)
  int bi = blockIdx.y;      // 0..15
  int z  = blockIdx.z;
  const float* Tz = Tinv + (size_t)z*NM;
  float* Wz = W + (size_t)z*NN*NW;
  __shared__ float At[64*68];    // transposed A: At[p*68 + r]
  __shared__ float Bs[64*132];   // Bs[p*132 + c]
  int tid = threadIdx.x;
  int ty = tid>>4, tx = tid&15;
  float areg[16], breg[32];
  float acc[4][8] = {};
  #pragma unroll
  for (int i=0;i<16;i++){
    int idx=i*256+tid, r=idx>>6, c=idx&63;
    areg[i] = Tz[(size_t)(bi*64+r)*NN + c];
  }
  #pragma unroll
  for (int i=0;i<32;i++){
    int idx=i*256+tid, r=idx>>7, c=idx&127;
    breg[i] = (ct<8) ? R[(size_t)r*NN + ct*128 + c]
                     : ((c<4) ? u[c*NN + r] : 0.f);
  }
  for (int kb=0; kb<=bi; kb++){
    __syncthreads();
    #pragma unroll
    for (int i=0;i<16;i++){
      int idx=i*256+tid, r=idx>>6, c=idx&63;
      At[c*68 + r] = areg[i];
    }
    #pragma unroll
    for (int i=0;i<32;i++){
      int idx=i*256+tid, r=idx>>7, c=idx&127;
      Bs[r*132 + c] = breg[i];
    }
    if (kb < bi){
      int kn = kb+1;
      #pragma unroll
      for (int i=0;i<16;i++){
        int idx=i*256+tid, r=idx>>6, c=idx&63;
        areg[i] = Tz[(size_t)(bi*64+r)*NN + kn*64 + c];
      }
      #pragma unroll
      for (int i=0;i<32;i++){
        int idx=i*256+tid, r=idx>>7, c=idx&127;
        int gr = kn*64 + r;
        breg[i] = (ct<8) ? R[(size_t)gr*NN + ct*128 + c]
                         : ((c<4) ? u[c*NN + gr] : 0.f);
      }
    }
    __syncthreads();
    for (int p=0;p<64;p++){
      float4 a4 = *(const float4*)&At[p*68 + ty*4];
      float4 b0 = *(const float4*)&Bs[p*132 + tx*8];
      float4 b1 = *(const float4*)&Bs[p*132 + tx*8 + 4];
      float ar[4]={a4.x,a4.y,a4.z,a4.w};
      float bc[8]={b0.x,b0.y,b0.z,b0.w,b1.x,b1.y,b1.z,b1.w};
      #pragma unroll
      for (int ii=0;ii<4;ii++)
        #pragma unroll
        for (int jj=0;jj<8;jj++) acc[ii][jj] += ar[ii]*bc[jj];
    }
  }
  #pragma unroll
  for (int ii=0;ii<4;ii++){
    size_t row = (size_t)(bi*64 + ty*4 + ii)*NW + ct*128 + tx*8;
    *(float4*)&Wz[row]   = make_float4(acc[ii][0],acc[ii][1],acc[ii][2],acc[ii][3]);
    *(float4*)&Wz[row+4] = make_float4(acc[ii][4],acc[ii][5],acc[ii][6],acc[ii][7]);
  }
}

// ---------------- zero Q accumulator ----------------
__global__ void k_zeroQ(float* __restrict__ Q)
{
  size_t i = ((size_t)blockIdx.x*256 + threadIdx.x)*4;
  *(float4*)&Q[i] = make_float4(0.f,0.f,0.f,0.f);
}

// ---------------- Q += W^T W partials (K-split 4), triangle tiles + mirror, atomics ----------------
__global__ __launch_bounds__(256) void k_WtW(const float* __restrict__ W, float* __restrict__ Q)
{
  int z = blockIdx.z;
  int ks = blockIdx.x / 36;               // 0..3, K chunk of 256
  int tt = blockIdx.x % 36, mi = 0;
  while (tt >= mi+1){ tt -= (mi+1); mi++; }
  int mj = tt;
  const float* Wz = W + (size_t)z*NN*NW;
  float* Qz = Q + (size_t)z*NM;
  int mi0 = mi*128, mj0 = mj*128;
  __shared__ float as[16*132];
  __shared__ float bs[16*132];
  int tid = threadIdx.x;
  int ty = tid>>4, tx = tid&15;
  float areg[8], breg[8];
  float acc[8][8] = {};
  int nbase = ks*256;
  #pragma unroll
  for (int i=0;i<8;i++){
    int idx=i*256+tid, r=idx>>7, c=idx&127;
    areg[i] = Wz[(size_t)(nbase+r)*NW + mi0 + c];
    breg[i] = Wz[(size_t)(nbase+r)*NW + mj0 + c];
  }
  for (int s=0;s<16;s++){
    __syncthreads();
    #pragma unroll
    for (int i=0;i<8;i++){
      int idx=i*256+tid, r=idx>>7, c=idx&127;
      as[r*132+c]=areg[i];
      bs[r*132+c]=breg[i];
    }
    if (s<15){
      int n0 = nbase + (s+1)*16;
      #pragma unroll
      for (int i=0;i<8;i++){
        int idx=i*256+tid, r=idx>>7, c=idx&127;
        areg[i] = Wz[(size_t)(n0+r)*NW + mi0 + c];
        breg[i] = Wz[(size_t)(n0+r)*NW + mj0 + c];
      }
    }
    __syncthreads();
    #pragma unroll
    for (int p=0;p<16;p++){
      float4 a0 = *(const float4*)&as[p*132 + ty*8];
      float4 a1 = *(const float4*)&as[p*132 + ty*8 + 4];
      float4 b0 = *(const float4*)&bs[p*132 + tx*8];
      float4 b1 = *(const float4*)&bs[p*132 + tx*8 + 4];
      float arf[8]={a0.x,a0.y,a0.z,a0.w,a1.x,a1.y,a1.z,a1.w};
      float bcf[8]={b0.x,b0.y,b0.z,b0.w,b1.x,b1.y,b1.z,b1.w};
      #pragma unroll
      for (int ii=0;ii<8;ii++)
        #pragma unroll
        for (int jj=0;jj<8;jj++) acc[ii][jj]+=arf[ii]*bcf[jj];
    }
  }
  for (int ii=0;ii<8;ii++){
    size_t row = (size_t)(mi0 + ty*8 + ii)*NN + mj0 + tx*8;
    #pragma unroll
    for (int jj=0;jj<8;jj++) atomicAdd(&Qz[row+jj], acc[ii][jj]);
  }
  if (mi != mj){
    for (int jj=0;jj<8;jj++){
      size_t row = (size_t)(mj0 + tx*8 + jj)*NN + mi0 + ty*8;
      #pragma unroll
      for (int ii=0;ii<8;ii++) atomicAdd(&Qz[row+ii], acc[ii][jj]);
    }
  }
}

// ---------------- column-dot partials ----------------
__global__ void k_colmul(const float* __restrict__ W, float* __restrict__ wpart)
{
  int mc = blockIdx.x, z = blockIdx.y, ns = blockIdx.z, tid = threadIdx.x;
  __shared__ float ufs[256];
  const float* Wz = W + (size_t)z*NN*NW;
  ufs[tid] = Wz[(size_t)(ns*256+tid)*NW + 1024 + z];
  __syncthreads();
  int m = mc*256 + tid;
  float acc = 0.f;
  for (int n=0;n<256;n++)
    acc += Wz[(size_t)(ns*256+n)*NW + m]*ufs[n];
  wpart[(size_t)(z*4+ns)*1024 + m] = acc;
}

// ---------------- fmean outputs (outputs 0 and 3) ----------------
__global__ void k_fmeanout(const float* __restrict__ wpart, const GPParams* __restrict__ P,
                           float* __restrict__ out)
{
  int m = blockIdx.x*256 + threadIdx.x;
  float w[4];
  #pragma unroll
  for (int i=0;i<4;i++){
    float s=0.f;
    #pragma unroll
    for (int ns=0;ns<4;ns++) s += wpart[(size_t)(i*4+ns)*1024 + m];
    w[i]=s;
  }
  #pragma unroll
  for (int a=0;a<4;a++){
    float fm = 0.f;
    #pragma unroll
    for (int i=0;i<4;i++) fm += P->G[a*4+i]*w[i];
    out[a*NN + m] = fm;
    out[OFF_M4 + (size_t)m*4 + a] = fm;
  }
}

// ---------------- fvar assembly (output 1) ----------------
__global__ void k_fvar(const float* __restrict__ S, const float* __restrict__ Q,
                       const GPParams* __restrict__ P, float* __restrict__ out)
{
  size_t idx = (size_t)blockIdx.x*256 + threadIdx.x;
  int m = (int)(idx>>10), mp = (int)(idx & 1023);
  float s = S[idx];
  float q[4];
  #pragma unroll
  for (int i=0;i<4;i++) q[i] = Q[(size_t)i*NM + idx];
  float* fv = out + OFF_FVAR;
  #pragma unroll
  for (int a=0;a<4;a++)
    #pragma unroll
    for (int b=0;b<4;b++){
      float val = P->tk[a*4+b]*s;
      #pragma unroll
      for (int i=0;i<4;i++) val -= P->G[a*4+i]*P->G[b*4+i]*q[i];
      fv[(size_t)(a*NN+m)*BIG + (size_t)b*NN + mp] = val;
    }
}

// ---------------- noise output (output 2) — reads only d_in, runs last ----------------
__global__ void k_noise(const float* __restrict__ logn, float* __restrict__ out)
{
  size_t idx = (size_t)blockIdx.x*256 + threadIdx.x;
  int row = (int)(idx>>12), col = (int)(idx & 4095);
  out[OFF_NOISE + idx] = (row==col) ? expf(logn[row>>10]) : 0.f;
}

extern "C" void kernel_launch(void* const* d_in, const int* in_sizes, int n_in,
                              void* d_out, int out_size, void* d_ws, size_t ws_size,
                              hipStream_t stream)
{
  const float* X    = (const float*)d_in[0];
  const float* tX   = (const float*)d_in[1];
  const float* Y    = (const float*)d_in[2];
  const float* logn = (const float*)d_in[3];
  const float* cf   = (const float*)d_in[4];
  const float* logv = (const float*)d_in[5];
  const float* logls= (const float*)d_in[6];
  float* out = (float*)d_out;

  // scratch (floats): P(64) u(4096) wpart(16384) R(NM) S(NM) M(4NM)[->Tinv]
  //                   Linv(262144) Gbuf(262144) Lbuf(4NM)[->Q] W(4*NN*NW)[tb]
  size_t need_floats = 64 + 4096 + 16384
                     + 2*(size_t)NM + 4*(size_t)NM + 262144 + 262144 + 4*(size_t)NM
                     + 4*(size_t)NN*NW;           // = 15,749,184
  float* base;
  if (ws_size >= (need_floats + 1024)*sizeof(float)) base = (float*)d_ws;
  else base = out + OFF_NOISE;  // noise region as scratch; k_noise runs last

  GPParams* P  = (GPParams*)base;
  float* u     = base + 64;
  float* wpart = u + 4096;
  float* R     = wpart + 16384;
  float* S     = R + NM;
  float* M     = S + NM;                       // chol workspace -> Tinv
  float* Linv  = M + 4*(size_t)NM;
  float* Gbuf  = Linv + 262144;
  float* Lbuf  = Gbuf + 262144;                // true L panels -> Q accumulator
  float* W     = Lbuf + 4*(size_t)NM;          // tb during doubling, then W
  float* Tinv  = M;
  float* Q     = Lbuf;
  float* tb    = W;

  dim3 b16(16,16);

  k_prep<<<1, 1, 0, stream>>>(logn, cf, logv, P);
  k_rbf <<<dim3(64,64), b16, 0, stream>>>(X,  tX, logls, R);
  k_rbf <<<dim3(64,64), b16, 0, stream>>>(tX, tX, logls, S);
  k_rbfM<<<dim3(64,64), b16, 0, stream>>>(X, logls, P, M);
  k_uvec<<<dim3(4), 256, 0, stream>>>(Y, P, u);

  // Cholesky: potf2(0) then 15 fused G-based syrk+factor steps
  k_potf2<<<dim3(4), 256, 0, stream>>>(M, Linv, Gbuf, 0);
  for (int k=0;k<NBLK-1;k++){
    int nb = NBLK-1-k;
    k_csf<<<dim3(nb*(nb+1)/2, 1, 4), 256, 0, stream>>>(M, Linv, Gbuf, Lbuf, k);
  }

  // full triangular inversion by doubling: Tinv = L^{-1} (in M region)
  k_dbl1<<<dim3(8,4), 256, 0, stream>>>(Lbuf, Linv, Tinv);
  for (int g64=2; g64<=8; g64*=2){
    int np = 8/g64;
    k_dblT<<<dim3(np*g64*g64, 4), 256, 0, stream>>>(Lbuf, Tinv, tb, g64);
    k_dblC<<<dim3(np*g64*g64, 4), 256, 0, stream>>>(tb, Tinv, g64);
  }

  // W = Tinv * [R | u]
  k_wgemm<<<dim3(9,16,4), 256, 0, stream>>>(Tinv, R, u, W);

  // Q = W^T W (atomic accumulate over 4 K-chunks)
  k_zeroQ<<<dim3(4096), 256, 0, stream>>>(Q);
  k_WtW<<<dim3(144,1,4), 256, 0, stream>>>(W, Q);

  k_colmul<<<dim3(4,4,4), 256, 0, stream>>>(W, wpart);
  k_fmeanout<<<dim3(4), 256, 0, stream>>>(wpart, P, out);
  k_fvar<<<dim3(NM/256), 256, 0, stream>>>(S, Q, P, out);
  k_noise<<<dim3(16777216/256), 256, 0, stream>>>(logn, out); // last: may overwrite scratch
}

// Round 7
// 1966.092 us; speedup vs baseline: 1.2925x; 1.2925x over previous
//
#include <hip/hip_runtime.h>
#include <math.h>

#define NN 1024
#define NM (NN*NN)
#define NB 64
#define NBLK 16
#define NW 1152
#define BIG 4096

#define OFF_FVAR  ((size_t)4096)
#define OFF_NOISE ((size_t)(4096 + 16777216))
#define OFF_M4    ((size_t)(4096 + 2*16777216))

// LDS column pad: +4 floats per 32 -> 4-way bank conflicts become 2-way (free)
#define CPAD(c) ((c) + (((c)>>5)<<2))
#define WSTRIDE 140

struct GPParams {
  float tk[16];   // task_K[a*4+b]
  float E[16];    // E[a*4+i]
  float G[16];    // G[a*4+i]
  float lam[4];
};

// ---------------- small setup: task_K, 4x4 Jacobi eigendecomp ----------------
__global__ void k_prep(const float* __restrict__ logn, const float* __restrict__ cf,
                       const float* __restrict__ logv, GPParams* __restrict__ P)
{
  if (threadIdx.x != 0 || blockIdx.x != 0) return;
  double tk[4][4], Dn[4], T[4][4], U[4][4];
  for (int a=0;a<4;a++) for (int b=0;b<4;b++){
    double s = 0.0;
    for (int r=0;r<2;r++) s += (double)cf[a*2+r]*(double)cf[b*2+r];
    if (a==b) s += exp((double)logv[a]);
    tk[a][b] = s;
  }
  for (int a=0;a<4;a++) Dn[a] = exp((double)logn[a]);
  for (int a=0;a<4;a++) for (int b=0;b<4;b++)
    T[a][b] = tk[a][b]/sqrt(Dn[a]*Dn[b]);
  for (int a=0;a<4;a++) for (int b=0;b<4;b++) U[a][b] = (a==b)?1.0:0.0;
  for (int sweep=0; sweep<40; sweep++){
    for (int p=0;p<3;p++) for (int q=p+1;q<4;q++){
      double apq = T[p][q];
      if (fabs(apq) < 1e-300) continue;
      double tau = (T[q][q]-T[p][p])/(2.0*apq);
      double t = (tau >= 0.0) ? 1.0/(tau + sqrt(1.0+tau*tau))
                              : 1.0/(tau - sqrt(1.0+tau*tau));
      double c = 1.0/sqrt(1.0+t*t), s = t*c;
      for (int k=0;k<4;k++){ double akp=T[k][p], akq=T[k][q];
        T[k][p]=c*akp - s*akq; T[k][q]=s*akp + c*akq; }
      for (int k=0;k<4;k++){ double apk=T[p][k], aqk=T[q][k];
        T[p][k]=c*apk - s*aqk; T[q][k]=s*apk + c*aqk; }
      for (int k=0;k<4;k++){ double ukp=U[k][p], ukq=U[k][q];
        U[k][p]=c*ukp - s*ukq; U[k][q]=s*ukp + c*ukq; }
    }
  }
  double E[4][4], G[4][4];
  for (int a=0;a<4;a++) for (int i=0;i<4;i++) E[a][i] = U[a][i]/sqrt(Dn[a]);
  for (int a=0;a<4;a++) for (int i=0;i<4;i++){
    double s=0; for (int b=0;b<4;b++) s += tk[a][b]*E[b][i];
    G[a][i]=s;
  }
  for (int a=0;a<4;a++) for (int b=0;b<4;b++){
    P->tk[a*4+b] = (float)tk[a][b];
    P->E [a*4+b] = (float)E[a][b];
    P->G [a*4+b] = (float)G[a][b];
  }
  for (int i=0;i<4;i++){
    double l = T[i][i];
    P->lam[i] = (float)(l > 0.0 ? l : 0.0);
  }
}

// ---------------- RBF kernel matrix ----------------
__global__ void k_rbf(const float* __restrict__ X1, const float* __restrict__ X2,
                      const float* __restrict__ logls, float* __restrict__ out)
{
  __shared__ float x1s[16][8];
  __shared__ float x2s[16][8];
  int tx = threadIdx.x, ty = threadIdx.y;
  int tid = ty*16 + tx;
  if (tid < 128){
    int r = tid>>3, d = tid&7;
    x1s[r][d] = X1[((size_t)blockIdx.y*16 + r)*8 + d];
  } else {
    int t2 = tid-128, r = t2>>3, d = t2&7;
    x2s[r][d] = X2[((size_t)blockIdx.x*16 + r)*8 + d];
  }
  __syncthreads();
  float ls2 = expf(2.0f*logls[0]);
  float d2 = 0.f;
  #pragma unroll
  for (int d=0; d<8; d++){ float df = x1s[ty][d]-x2s[tx][d]; d2 += df*df; }
  int i = blockIdx.y*16+ty, j = blockIdx.x*16+tx;
  out[(size_t)i*NN + j] = expf(-0.5f*d2/ls2);
}

// ---------------- rbf(X,X) fused with M_z = lam_z * C + I ----------------
__global__ void k_rbfM(const float* __restrict__ X1, const float* __restrict__ logls,
                       const GPParams* __restrict__ P, float* __restrict__ M)
{
  __shared__ float x1s[16][8];
  __shared__ float x2s[16][8];
  int tx = threadIdx.x, ty = threadIdx.y;
  int tid = ty*16 + tx;
  if (tid < 128){
    int r = tid>>3, d = tid&7;
    x1s[r][d] = X1[((size_t)blockIdx.y*16 + r)*8 + d];
  } else {
    int t2 = tid-128, r = t2>>3, d = t2&7;
    x2s[r][d] = X1[((size_t)blockIdx.x*16 + r)*8 + d];
  }
  __syncthreads();
  float ls2 = expf(2.0f*logls[0]);
  float d2 = 0.f;
  #pragma unroll
  for (int d=0; d<8; d++){ float df = x1s[ty][d]-x2s[tx][d]; d2 += df*df; }
  int i = blockIdx.y*16+ty, j = blockIdx.x*16+tx;
  float v = expf(-0.5f*d2/ls2);
  float diag = (i==j) ? 1.f : 0.f;
  size_t idx = (size_t)i*NN + j;
  #pragma unroll
  for (int z=0;z<4;z++)
    M[(size_t)z*NM + idx] = P->lam[z]*v + diag;
}

// ---------------- u_i = sum_a E[a][i] * Y[:,a] ----------------
__global__ void k_uvec(const float* __restrict__ Y, const GPParams* __restrict__ P,
                       float* __restrict__ u)
{
  int n = blockIdx.x*256 + threadIdx.x;
  float y0 = Y[n*4+0], y1 = Y[n*4+1], y2 = Y[n*4+2], y3 = Y[n*4+3];
  #pragma unroll
  for (int i=0;i<4;i++)
    u[i*NN + n] = P->E[0*4+i]*y0 + P->E[1*4+i]*y1 + P->E[2*4+i]*y2 + P->E[3*4+i]*y3;
}

// ---------------- 4x4-microtile 64-K GEMMs from LDS ----------------
__device__ __forceinline__ void gemm64(const float* __restrict__ A, const float* __restrict__ B,
                                       float acc[4][4], int r0, int c0, bool sub)
{
  for (int p=0;p<64;p++){
    float ar[4], bc[4];
    #pragma unroll
    for (int ii=0;ii<4;ii++) ar[ii]=A[(r0+ii)*65+p];
    #pragma unroll
    for (int jj=0;jj<4;jj++) bc[jj]=B[p*65+c0+jj];
    if (sub){
      #pragma unroll
      for (int ii=0;ii<4;ii++)
        #pragma unroll
        for (int jj=0;jj<4;jj++) acc[ii][jj] -= ar[ii]*bc[jj];
    } else {
      #pragma unroll
      for (int ii=0;ii<4;ii++)
        #pragma unroll
        for (int jj=0;jj<4;jj++) acc[ii][jj] += ar[ii]*bc[jj];
    }
  }
}
// acc += A[r][p] * B[c][p]   (A * B^T)
__device__ __forceinline__ void gemm64T(const float* __restrict__ A, const float* __restrict__ B,
                                        float acc[4][4], int r0, int c0)
{
  for (int p=0;p<64;p++){
    float ar[4], bc[4];
    #pragma unroll
    for (int ii=0;ii<4;ii++) ar[ii]=A[(r0+ii)*65+p];
    #pragma unroll
    for (int jj=0;jj<4;jj++) bc[jj]=B[(c0+jj)*65+p];
    #pragma unroll
    for (int ii=0;ii<4;ii++)
      #pragma unroll
      for (int jj=0;jj<4;jj++) acc[ii][jj] += ar[ii]*bc[jj];
  }
}

// ---------------- parallel inversion of lower-triangular 64x64 (stride 65) ----------------
// L: input (stride 65). inv: output (stride 65, fully written incl. zeros).
// tmp: >=1024 floats scratch. Needs all 256 threads; contains barriers.
__device__ __forceinline__ void inv_lower64(const float* __restrict__ L,
                                            float* __restrict__ inv,
                                            float* __restrict__ tmp, int tid)
{
  for (int idx=tid; idx<4160; idx+=256) inv[idx]=0.f;
  __syncthreads();
  // 8 diagonal 8x8 blocks: thread t = b*8+c does forward substitution for column c
  if (tid < 64){
    int b = tid>>3, c = tid&7, base=b*8;
    for (int r=c;r<8;r++){
      float s = (r==c)?1.f:0.f;
      for (int j=c;j<r;j++) s -= L[(base+r)*65 + base+j]*inv[(base+j)*65 + base+c];
      inv[(base+r)*65 + base+c] = s / L[(base+r)*65 + base+r];
    }
  }
  __syncthreads();
  // doubling: bs = 8,16,32.  inv21 = -inv22 * (L21 * inv11)
  for (int bs=8; bs<=32; bs<<=1){
    int npair = 32/bs;
    int nout = npair*bs*bs;
    for (int idx=tid; idx<nout; idx+=256){
      int p0 = idx/(bs*bs), rem = idx%(bs*bs);
      int r = rem/bs, c = rem%bs, base = p0*2*bs;
      float s=0.f;
      for (int j=c;j<bs;j++)
        s += L[(base+bs+r)*65 + base+j]*inv[(base+j)*65 + base+c];
      tmp[idx]=s;
    }
    __syncthreads();
    for (int idx=tid; idx<nout; idx+=256){
      int p0 = idx/(bs*bs), rem = idx%(bs*bs);
      int r = rem/bs, c = rem%bs, base = p0*2*bs;
      float s=0.f;
      for (int j=0;j<=r;j++)
        s += inv[(base+bs+r)*65 + base+bs+j]*tmp[p0*bs*bs + j*bs + c];
      inv[(base+bs+r)*65 + base+c] = -s;
    }
    __syncthreads();
  }
}

// ---------------- Cholesky diag k: factor 64x64 + inversion + G = Linv^T Linv ----------------
__global__ __launch_bounds__(256) void k_potf2(float* __restrict__ M, float* __restrict__ Linv,
                                               float* __restrict__ Gbuf, int k)
{
  int z = blockIdx.x, tid = threadIdx.x;
  __shared__ float a[64*65];    // unscaled working copy -> later Linv
  __shared__ float lo[64*65];   // scaled L
  __shared__ float tmp[1024];
  float* Mz = M + (size_t)z*NM;
  int base = k*NB;
  for (int idx=tid; idx<4096; idx+=256){
    int r=idx>>6, c=idx&63;
    a[r*65+c] = Mz[(size_t)(base+r)*NN + base + c];
  }
  int r = tid & 63, q = tid >> 6;
  for (int j=0;j<64;j++){
    __syncthreads();
    float d = a[j*65+j];
    float invd = 1.f/d;
    float rs = rsqrtf(d);
    if (q==0){
      if (r == j) lo[j*65+j] = sqrtf(d);
      else if (r > j) lo[r*65+j] = a[r*65+j]*rs;
      else lo[r*65+j] = 0.f;
    }
    if (r > j){
      float lrj = a[r*65+j]*invd;
      for (int c=j+1+q; c<=r; c+=4)
        a[r*65+c] -= lrj * a[c*65+j];
    }
  }
  __syncthreads();
  inv_lower64(lo, a, tmp, tid);         // a = Linv
  float* Lg = Linv + ((size_t)z*NBLK + k)*(NB*NB);
  float* Td = Mz + (size_t)base*NN + base;
  for (int idx=tid; idx<4096; idx+=256){
    int rr=idx>>6, c=idx&63;
    float v = a[rr*65+c];
    Lg[rr*64+c] = v;
    Td[(size_t)rr*NN + c] = v;
  }
  // G = Linv^T Linv
  {
    int r0=(tid>>4)*4, c0=(tid&15)*4;
    float g[4][4]={};
    for (int p=0;p<64;p++){
      float ar[4], bc[4];
      #pragma unroll
      for (int ii=0;ii<4;ii++) ar[ii]=a[p*65+r0+ii];
      #pragma unroll
      for (int jj=0;jj<4;jj++) bc[jj]=a[p*65+c0+jj];
      #pragma unroll
      for (int ii=0;ii<4;ii++)
        #pragma unroll
        for (int jj=0;jj<4;jj++) g[ii][jj]+=ar[ii]*bc[jj];
    }
    float* Gg = Gbuf + ((size_t)z*NBLK + k)*4096;
    #pragma unroll
    for (int ii=0;ii<4;ii++)
      *(float4*)&Gg[(r0+ii)*64 + c0] = make_float4(g[ii][0],g[ii][1],g[ii][2],g[ii][3]);
  }
}

// ------- fused chol step k (G-based): tiles do M[bi][bj] -= P_bi * G * P_bj^T;
// ------- first-column tiles archive scaled panel; the (k+1,k+1) block factors.
__global__ __launch_bounds__(256) void k_csf(float* __restrict__ M, float* __restrict__ Linv,
                                             float* __restrict__ Gbuf, float* __restrict__ Lbuf, int k)
{
  int z = blockIdx.z;
  int tt = blockIdx.x, i2 = 0;
  while (tt >= i2+1){ tt -= (i2+1); i2++; }
  int bi = k+1+i2, bj = k+1+tt;
  bool fblk = (i2==0);               // bi==bj==k+1
  __shared__ float pa[64*65];
  __shared__ float pb[64*65];
  __shared__ float li[64*65];
  float* Mz = M + (size_t)z*NM;
  float* Lb = Lbuf + (size_t)z*NM;
  int tid = threadIdx.x;
  int ty = tid>>4, tx = tid&15;
  int r0 = ty*4, c0 = tx*4;

  if (fblk){
    const float* Lg = Linv + ((size_t)z*NBLK + k)*(NB*NB);
    for (int idx=tid; idx<4096; idx+=256){
      int r=idx>>6, c=idx&63;
      li[r*65+c] = Lg[idx];
      pa[r*65+c] = Mz[(size_t)(bi*64+r)*NN + k*64 + c];   // raw panel
      pb[r*65+c] = Mz[(size_t)(bi*64+r)*NN + bi*64 + c];  // raw diag
    }
    __syncthreads();
    float sc[4][4]={};
    gemm64T(pa, li, sc, r0, c0);         // scaled = P * Linv^T
    #pragma unroll
    for (int ii=0;ii<4;ii++)
      *(float4*)&Lb[(size_t)(bi*64+r0+ii)*NN + k*64+c0] =
        make_float4(sc[ii][0],sc[ii][1],sc[ii][2],sc[ii][3]);
    __syncthreads();
    #pragma unroll
    for (int ii=0;ii<4;ii++)
      #pragma unroll
      for (int jj=0;jj<4;jj++) pa[(r0+ii)*65+c0+jj] = sc[ii][jj];
    __syncthreads();
    float upd[4][4]={};
    gemm64T(pa, pa, upd, r0, c0);        // scaled * scaled^T
    #pragma unroll
    for (int ii=0;ii<4;ii++)
      #pragma unroll
      for (int jj=0;jj<4;jj++) pb[(r0+ii)*65+c0+jj] -= upd[ii][jj];
    // factor pb, write scaled L into li
    int r = tid & 63, q = tid >> 6;
    for (int j=0;j<64;j++){
      __syncthreads();
      float d = pb[j*65+j];
      float invd = 1.f/d;
      float rs = rsqrtf(d);
      if (q==0){
        if (r == j) li[j*65+j] = sqrtf(d);
        else if (r > j) li[r*65+j] = pb[r*65+j]*rs;
        else li[r*65+j] = 0.f;
      }
      if (r > j){
        float lrj = pb[r*65+j]*invd;
        for (int c=j+1+q; c<=r; c+=4)
          pb[r*65+c] -= lrj * pb[c*65+j];
      }
    }
    __syncthreads();
    inv_lower64(li, pa, pb, tid);        // pa = Linv(k+1); pb[0..1023] scratch
    float* Lg2 = Linv + ((size_t)z*NBLK + (k+1))*(NB*NB);
    float* Td  = Mz + (size_t)(bi*64)*NN + bi*64;
    for (int idx=tid; idx<4096; idx+=256){
      int rr=idx>>6, c=idx&63;
      float v = pa[rr*65+c];
      Lg2[rr*64+c] = v;
      Td[(size_t)rr*NN + c] = v;
    }
    // G_{k+1} = Linv^T Linv
    {
      float g[4][4]={};
      for (int p=0;p<64;p++){
        float ar[4], bc[4];
        #pragma unroll
        for (int ii=0;ii<4;ii++) ar[ii]=pa[p*65+r0+ii];
        #pragma unroll
        for (int jj=0;jj<4;jj++) bc[jj]=pa[p*65+c0+jj];
        #pragma unroll
        for (int ii=0;ii<4;ii++)
          #pragma unroll
          for (int jj=0;jj<4;jj++) g[ii][jj]+=ar[ii]*bc[jj];
      }
      float* Gg = Gbuf + ((size_t)z*NBLK + (k+1))*4096;
      #pragma unroll
      for (int ii=0;ii<4;ii++)
        *(float4*)&Gg[(r0+ii)*64 + c0] = make_float4(g[ii][0],g[ii][1],g[ii][2],g[ii][3]);
    }
    return;
  }

  // ---- general tile: M[bi][bj] -= P_bi * G * P_bj^T ----
  const float* Gg = Gbuf + ((size_t)z*NBLK + k)*4096;
  for (int idx=tid; idx<4096; idx+=256){
    int r=idx>>6, c=idx&63;
    li[r*65+c] = Gg[idx];
    pa[r*65+c] = Mz[(size_t)(bi*64+r)*NN + k*64 + c];
    pb[r*65+c] = Mz[(size_t)(bj*64+r)*NN + k*64 + c];
  }
  __syncthreads();
  float t[4][4]={};
  gemm64(pa, li, t, r0, c0, false);      // t = P_bi * G
  __syncthreads();
  #pragma unroll
  for (int ii=0;ii<4;ii++)
    #pragma unroll
    for (int jj=0;jj<4;jj++) li[(r0+ii)*65+c0+jj] = t[ii][jj];
  __syncthreads();
  float upd[4][4]={};
  gemm64T(li, pb, upd, r0, c0);          // t * P_bj^T
  #pragma unroll
  for (int ii=0;ii<4;ii++){
    float4* ptr = (float4*)&Mz[(size_t)(bi*64+r0+ii)*NN + bj*64+c0];
    float4 v = *ptr;
    v.x-=upd[ii][0]; v.y-=upd[ii][1]; v.z-=upd[ii][2]; v.w-=upd[ii][3];
    *ptr = v;
  }
  if (bj == k+1){
    __syncthreads();
    const float* Lg = Linv + ((size_t)z*NBLK + k)*(NB*NB);
    for (int idx=tid; idx<4096; idx+=256){
      int r=idx>>6, c=idx&63;
      pb[r*65+c] = Lg[idx];
    }
    __syncthreads();
    float sc[4][4]={};
    gemm64T(pa, pb, sc, r0, c0);
    #pragma unroll
    for (int ii=0;ii<4;ii++)
      *(float4*)&Lb[(size_t)(bi*64+r0+ii)*NN + k*64+c0] =
        make_float4(sc[ii][0],sc[ii][1],sc[ii][2],sc[ii][3]);
  }
}

// ---------------- doubling step 1 (fused): Tinv(2p+1,2p) = -Binv * L21 * Ainv ----------------
__global__ __launch_bounds__(256) void k_dbl1(const float* __restrict__ Lbuf,
                                              const float* __restrict__ Linv,
                                              float* __restrict__ Tinv)
{
  int pair = blockIdx.x, z = blockIdx.y, tid = threadIdx.x;
  int b0 = 2*pair, b1 = 2*pair+1;
  __shared__ float l21[64*65];
  __shared__ float ai[64*65];
  __shared__ float tt[64*65];
  const float* Lb = Lbuf + (size_t)z*NM;
  const float* La = Linv + ((size_t)z*NBLK + b0)*(NB*NB);
  const float* Lc = Linv + ((size_t)z*NBLK + b1)*(NB*NB);
  for (int idx=tid; idx<4096; idx+=256){
    int r=idx>>6, c=idx&63;
    l21[r*65+c] = Lb[(size_t)(b1*64+r)*NN + b0*64 + c];
    ai[r*65+c]  = La[idx];
  }
  __syncthreads();
  int ty=tid>>4, tx=tid&15, r0=ty*4, c0=tx*4;
  float acc[4][4]={};
  gemm64(l21, ai, acc, r0, c0, false);
  __syncthreads();
  #pragma unroll
  for (int ii=0;ii<4;ii++)
    #pragma unroll
    for (int jj=0;jj<4;jj++) tt[(r0+ii)*65 + c0+jj] = acc[ii][jj];
  for (int idx=tid; idx<4096; idx+=256){
    int r=idx>>6, c=idx&63;
    ai[r*65+c] = Lc[idx];
  }
  __syncthreads();
  float fin[4][4]={};
  gemm64(ai, tt, fin, r0, c0, false);
  float* Tz = Tinv + (size_t)z*NM;
  #pragma unroll
  for (int ii=0;ii<4;ii++){
    float4 v = make_float4(-fin[ii][0],-fin[ii][1],-fin[ii][2],-fin[ii][3]);
    *(float4*)&Tz[(size_t)(b1*64+r0+ii)*NN + b0*64+c0] = v;
  }
}

// ---------------- doubling: t = L21 * Tinv11 ----------------
__global__ __launch_bounds__(256) void k_dblT(const float* __restrict__ Lbuf,
                                              const float* __restrict__ Tinv,
                                              float* __restrict__ tb, int g64)
{
  int z = blockIdx.y, tid = threadIdx.x;
  int tpp = g64*g64;
  int pair = blockIdx.x / tpp;
  int tt2 = blockIdx.x % tpp;
  int ti = tt2 / g64, tj = tt2 % g64;
  int b0 = 2*pair*g64, b1 = b0 + g64;
  const float* Lb = Lbuf + (size_t)z*NM;
  const float* Tz = Tinv + (size_t)z*NM;
  __shared__ float lt[64*65];
  __shared__ float rt[64*65];
  int ty=tid>>4, tx=tid&15, r0=ty*4, c0=tx*4;
  float acc[4][4]={};
  for (int kb=tj; kb<g64; kb++){
    for (int idx=tid; idx<4096; idx+=256){
      int r=idx>>6, c=idx&63;
      lt[r*65+c] = Lb[(size_t)((b1+ti)*64+r)*NN + (b0+kb)*64 + c];
      rt[r*65+c] = Tz[(size_t)((b0+kb)*64+r)*NN + (b0+tj)*64 + c];
    }
    __syncthreads();
    gemm64(lt, rt, acc, r0, c0, false);
    __syncthreads();
  }
  int g = g64*64;
  float* tz = tb + (size_t)z*262144 + (size_t)pair*g*g;
  #pragma unroll
  for (int ii=0;ii<4;ii++){
    float4 v = make_float4(acc[ii][0],acc[ii][1],acc[ii][2],acc[ii][3]);
    *(float4*)&tz[(size_t)(ti*64+r0+ii)*g + tj*64+c0] = v;
  }
}

// ---------------- doubling: Tinv21 = -Tinv22 * t ----------------
__global__ __launch_bounds__(256) void k_dblC(const float* __restrict__ tb,
                                              float* __restrict__ Tinv, int g64)
{
  int z = blockIdx.y, tid = threadIdx.x;
  int tpp = g64*g64;
  int pair = blockIdx.x / tpp;
  int tt2 = blockIdx.x % tpp;
  int ti = tt2 / g64, tj = tt2 % g64;
  int b0 = 2*pair*g64, b1 = b0 + g64;
  float* Tz = Tinv + (size_t)z*NM;
  int g = g64*64;
  const float* tz = tb + (size_t)z*262144 + (size_t)pair*g*g;
  __shared__ float lt[64*65];
  __shared__ float rt[64*65];
  int ty=tid>>4, tx=tid&15, r0=ty*4, c0=tx*4;
  float acc[4][4]={};
  for (int kb=0; kb<=ti; kb++){
    for (int idx=tid; idx<4096; idx+=256){
      int r=idx>>6, c=idx&63;
      lt[r*65+c] = Tz[(size_t)((b1+ti)*64+r)*NN + (b1+kb)*64 + c];
      rt[r*65+c] = tz[(size_t)(kb*64+r)*g + tj*64 + c];
    }
    __syncthreads();
    gemm64(lt, rt, acc, r0, c0, false);
    __syncthreads();
  }
  #pragma unroll
  for (int ii=0;ii<4;ii++){
    float4 v = make_float4(-acc[ii][0],-acc[ii][1],-acc[ii][2],-acc[ii][3]);
    *(float4*)&Tz[(size_t)((b1+ti)*64+r0+ii)*NN + b0*64+tj*64+c0] = v;
  }
}

// ---------------- W = Tinv * [R | u] : 64x128 tiles, 4x8 micro, reg prefetch ----------------
__global__ __launch_bounds__(256) void k_wgemm(const float* __restrict__ Tinv,
                                               const float* __restrict__ R,
                                               const float* __restrict__ u,
                                               float* __restrict__ W)
{
  int ct = blockIdx.x;      // 0..8 (8 = u/pad tile)
  int bi = blockIdx.y;      // 0..15
  int z  = blockIdx.z;
  const float* Tz = Tinv + (size_t)z*NM;
  float* Wz = W + (size_t)z*NN*NW;
  __shared__ float At[64*68];    // transposed A: At[p*68 + r]
  __shared__ float Bs[64*132];   // Bs[p*132 + c]
  int tid = threadIdx.x;
  int ty = tid>>4, tx = tid&15;
  float areg[16], breg[32];
  float acc[4][8] = {};
  #pragma unroll
  for (int i=0;i<16;i++){
    int idx=i*256+tid, r=idx>>6, c=idx&63;
    areg[i] = Tz[(size_t)(bi*64+r)*NN + c];
  }
  #pragma unroll
  for (int i=0;i<32;i++){
    int idx=i*256+tid, r=idx>>7, c=idx&127;
    breg[i] = (ct<8) ? R[(size_t)r*NN + ct*128 + c]
                     : ((c<4) ? u[c*NN + r] : 0.f);
  }
  for (int kb=0; kb<=bi; kb++){
    __syncthreads();
    #pragma unroll
    for (int i=0;i<16;i++){
      int idx=i*256+tid, r=idx>>6, c=idx&63;
      At[c*68 + r] = areg[i];
    }
    #pragma unroll
    for (int i=0;i<32;i++){
      int idx=i*256+tid, r=idx>>7, c=idx&127;
      Bs[r*132 + c] = breg[i];
    }
    if (kb < bi){
      int kn = kb+1;
      #pragma unroll
      for (int i=0;i<16;i++){
        int idx=i*256+tid, r=idx>>6, c=idx&63;
        areg[i] = Tz[(size_t)(bi*64+r)*NN + kn*64 + c];
      }
      #pragma unroll
      for (int i=0;i<32;i++){
        int idx=i*256+tid, r=idx>>7, c=idx&127;
        int gr = kn*64 + r;
        breg[i] = (ct<8) ? R[(size_t)gr*NN + ct*128 + c]
                         : ((c<4) ? u[c*NN + gr] : 0.f);
      }
    }
    __syncthreads();
    for (int p=0;p<64;p++){
      float4 a4 = *(const float4*)&At[p*68 + ty*4];
      float4 b0 = *(const float4*)&Bs[p*132 + tx*8];
      float4 b1 = *(const float4*)&Bs[p*132 + tx*8 + 4];
      float ar[4]={a4.x,a4.y,a4.z,a4.w};
      float bc[8]={b0.x,b0.y,b0.z,b0.w,b1.x,b1.y,b1.z,b1.w};
      #pragma unroll
      for (int ii=0;ii<4;ii++)
        #pragma unroll
        for (int jj=0;jj<8;jj++) acc[ii][jj] += ar[ii]*bc[jj];
    }
  }
  #pragma unroll
  for (int ii=0;ii<4;ii++){
    size_t row = (size_t)(bi*64 + ty*4 + ii)*NW + ct*128 + tx*8;
    *(float4*)&Wz[row]   = make_float4(acc[ii][0],acc[ii][1],acc[ii][2],acc[ii][3]);
    *(float4*)&Wz[row+4] = make_float4(acc[ii][4],acc[ii][5],acc[ii][6],acc[ii][7]);
  }
}

// ---------------- Q partials = W^T W (half-K split), triangle tiles + mirror, padded LDS ----------------
__global__ __launch_bounds__(256) void k_WtW(const float* __restrict__ W,
                                             float* __restrict__ Qa, float* __restrict__ Qb)
{
  int z = blockIdx.z;
  int ks = blockIdx.x / 36;
  int tt = blockIdx.x % 36, mi = 0;
  while (tt >= mi+1){ tt -= (mi+1); mi++; }
  int mj = tt;
  const float* Wz = W + (size_t)z*NN*NW;
  float* Qz = (ks ? Qb : Qa) + (size_t)z*NM;
  int mi0 = mi*128, mj0 = mj*128;
  __shared__ float as[16*WSTRIDE];
  __shared__ float bs[16*WSTRIDE];
  int tid = threadIdx.x;
  int ty = tid>>4, tx = tid&15;
  float areg[8], breg[8];
  float acc[8][8] = {};
  int nbase = ks*512;
  #pragma unroll
  for (int i=0;i<8;i++){
    int idx=i*256+tid, r=idx>>7, c=idx&127;
    areg[i] = Wz[(size_t)(nbase+r)*NW + mi0 + c];
    breg[i] = Wz[(size_t)(nbase+r)*NW + mj0 + c];
  }
  int ca = CPAD(ty*8), cb = CPAD(tx*8);
  for (int s=0;s<32;s++){
    __syncthreads();
    #pragma unroll
    for (int i=0;i<8;i++){
      int idx=i*256+tid, r=idx>>7, c=idx&127;
      as[r*WSTRIDE+CPAD(c)]=areg[i];
      bs[r*WSTRIDE+CPAD(c)]=breg[i];
    }
    if (s<31){
      int n0 = nbase + (s+1)*16;
      #pragma unroll
      for (int i=0;i<8;i++){
        int idx=i*256+tid, r=idx>>7, c=idx&127;
        areg[i] = Wz[(size_t)(n0+r)*NW + mi0 + c];
        breg[i] = Wz[(size_t)(n0+r)*NW + mj0 + c];
      }
    }
    __syncthreads();
    #pragma unroll
    for (int p=0;p<16;p++){
      float4 a0 = *(const float4*)&as[p*WSTRIDE + ca];
      float4 a1 = *(const float4*)&as[p*WSTRIDE + ca + 4];
      float4 b0 = *(const float4*)&bs[p*WSTRIDE + cb];
      float4 b1 = *(const float4*)&bs[p*WSTRIDE + cb + 4];
      float arf[8]={a0.x,a0.y,a0.z,a0.w,a1.x,a1.y,a1.z,a1.w};
      float bcf[8]={b0.x,b0.y,b0.z,b0.w,b1.x,b1.y,b1.z,b1.w};
      #pragma unroll
      for (int ii=0;ii<8;ii++)
        #pragma unroll
        for (int jj=0;jj<8;jj++) acc[ii][jj]+=arf[ii]*bcf[jj];
    }
  }
  for (int ii=0;ii<8;ii++){
    size_t row = (size_t)(mi0 + ty*8 + ii)*NN + mj0 + tx*8;
    *(float4*)&Qz[row]   = make_float4(acc[ii][0],acc[ii][1],acc[ii][2],acc[ii][3]);
    *(float4*)&Qz[row+4] = make_float4(acc[ii][4],acc[ii][5],acc[ii][6],acc[ii][7]);
  }
  if (mi != mj){
    for (int jj=0;jj<8;jj++){
      size_t row = (size_t)(mj0 + tx*8 + jj)*NN + mi0 + ty*8;
      *(float4*)&Qz[row]   = make_float4(acc[0][jj],acc[1][jj],acc[2][jj],acc[3][jj]);
      *(float4*)&Qz[row+4] = make_float4(acc[4][jj],acc[5][jj],acc[6][jj],acc[7][jj]);
    }
  }
}

// ---------------- column-dot partials ----------------
__global__ void k_colmul(const float* __restrict__ W, float* __restrict__ wpart)
{
  int mc = blockIdx.x, z = blockIdx.y, ns = blockIdx.z, tid = threadIdx.x;
  __shared__ float ufs[256];
  const float* Wz = W + (size_t)z*NN*NW;
  ufs[tid] = Wz[(size_t)(ns*256+tid)*NW + 1024 + z];
  __syncthreads();
  int m = mc*256 + tid;
  float acc = 0.f;
  for (int n=0;n<256;n++)
    acc += Wz[(size_t)(ns*256+n)*NW + m]*ufs[n];
  wpart[(size_t)(z*4+ns)*1024 + m] = acc;
}

// ---------------- fmean outputs (outputs 0 and 3) ----------------
__global__ void k_fmeanout(const float* __restrict__ wpart, const GPParams* __restrict__ P,
                           float* __restrict__ out)
{
  int m = blockIdx.x*256 + threadIdx.x;
  float w[4];
  #pragma unroll
  for (int i=0;i<4;i++){
    float s=0.f;
    #pragma unroll
    for (int ns=0;ns<4;ns++) s += wpart[(size_t)(i*4+ns)*1024 + m];
    w[i]=s;
  }
  #pragma unroll
  for (int a=0;a<4;a++){
    float fm = 0.f;
    #pragma unroll
    for (int i=0;i<4;i++) fm += P->G[a*4+i]*w[i];
    out[a*NN + m] = fm;
    out[OFF_M4 + (size_t)m*4 + a] = fm;
  }
}

// ---------------- fvar assembly (output 1) ----------------
__global__ void k_fvar(const float* __restrict__ S, const float* __restrict__ Qa,
                       const float* __restrict__ Qb, const GPParams* __restrict__ P,
                       float* __restrict__ out)
{
  size_t idx = (size_t)blockIdx.x*256 + threadIdx.x;
  int m = (int)(idx>>10), mp = (int)(idx & 1023);
  float s = S[idx];
  float q[4];
  #pragma unroll
  for (int i=0;i<4;i++) q[i] = Qa[(size_t)i*NM + idx] + Qb[(size_t)i*NM + idx];
  float* fv = out + OFF_FVAR;
  #pragma unroll
  for (int a=0;a<4;a++)
    #pragma unroll
    for (int b=0;b<4;b++){
      float val = P->tk[a*4+b]*s;
      #pragma unroll
      for (int i=0;i<4;i++) val -= P->G[a*4+i]*P->G[b*4+i]*q[i];
      fv[(size_t)(a*NN+m)*BIG + (size_t)b*NN + mp] = val;
    }
}

// ---------------- noise output (output 2) — reads only d_in, runs last ----------------
__global__ void k_noise(const float* __restrict__ logn, float* __restrict__ out)
{
  size_t idx = (size_t)blockIdx.x*256 + threadIdx.x;
  int row = (int)(idx>>12), col = (int)(idx & 4095);
  out[OFF_NOISE + idx] = (row==col) ? expf(logn[row>>10]) : 0.f;
}

extern "C" void kernel_launch(void* const* d_in, const int* in_sizes, int n_in,
                              void* d_out, int out_size, void* d_ws, size_t ws_size,
                              hipStream_t stream)
{
  const float* X    = (const float*)d_in[0];
  const float* tX   = (const float*)d_in[1];
  const float* Y    = (const float*)d_in[2];
  const float* logn = (const float*)d_in[3];
  const float* cf   = (const float*)d_in[4];
  const float* logv = (const float*)d_in[5];
  const float* logls= (const float*)d_in[6];
  float* out = (float*)d_out;

  // scratch (floats): P(64) u(4096) wpart(16384) R(NM) S(NM) M(4NM)[->Tinv->Qa]
  //                   Linv(262144) Gbuf(262144) Lbuf(4NM)[->Qb] W(4*NN*NW)[tb]
  size_t need_floats = 64 + 4096 + 16384
                     + 2*(size_t)NM + 4*(size_t)NM + 262144 + 262144 + 4*(size_t)NM
                     + 4*(size_t)NN*NW;
  float* base;
  if (ws_size >= (need_floats + 1024)*sizeof(float)) base = (float*)d_ws;
  else base = out + OFF_NOISE;  // noise region as scratch; k_noise runs last

  GPParams* P  = (GPParams*)base;
  float* u     = base + 64;
  float* wpart = u + 4096;
  float* R     = wpart + 16384;
  float* S     = R + NM;
  float* M     = S + NM;                       // chol workspace -> Tinv -> Qa
  float* Linv  = M + 4*(size_t)NM;
  float* Gbuf  = Linv + 262144;
  float* Lbuf  = Gbuf + 262144;                // true L panels -> Qb
  float* W     = Lbuf + 4*(size_t)NM;          // tb during doubling, then W
  float* Tinv  = M;
  float* Qa    = M;
  float* Qb    = Lbuf;
  float* tb    = W;

  dim3 b16(16,16);

  k_prep<<<1, 1, 0, stream>>>(logn, cf, logv, P);
  k_rbf <<<dim3(64,64), b16, 0, stream>>>(X,  tX, logls, R);
  k_rbf <<<dim3(64,64), b16, 0, stream>>>(tX, tX, logls, S);
  k_rbfM<<<dim3(64,64), b16, 0, stream>>>(X, logls, P, M);
  k_uvec<<<dim3(4), 256, 0, stream>>>(Y, P, u);

  // Cholesky: potf2(0) then 15 fused G-based syrk+factor steps
  k_potf2<<<dim3(4), 256, 0, stream>>>(M, Linv, Gbuf, 0);
  for (int k=0;k<NBLK-1;k++){
    int nb = NBLK-1-k;
    k_csf<<<dim3(nb*(nb+1)/2, 1, 4), 256, 0, stream>>>(M, Linv, Gbuf, Lbuf, k);
  }

  // full triangular inversion by doubling: Tinv = L^{-1} (in M region)
  k_dbl1<<<dim3(8,4), 256, 0, stream>>>(Lbuf, Linv, Tinv);
  for (int g64=2; g64<=8; g64*=2){
    int np = 8/g64;
    k_dblT<<<dim3(np*g64*g64, 4), 256, 0, stream>>>(Lbuf, Tinv, tb, g64);
    k_dblC<<<dim3(np*g64*g64, 4), 256, 0, stream>>>(tb, Tinv, g64);
  }

  // W = Tinv * [R | u]
  k_wgemm<<<dim3(9,16,4), 256, 0, stream>>>(Tinv, R, u, W);

  // Q = W^T W (two half-K partials into Qa/Qb)
  k_WtW<<<dim3(72,1,4), 256, 0, stream>>>(W, Qa, Qb);

  k_colmul<<<dim3(4,4,4), 256, 0, stream>>>(W, wpart);
  k_fmeanout<<<dim3(4), 256, 0, stream>>>(wpart, P, out);
  k_fvar<<<dim3(NM/256), 256, 0, stream>>>(S, Qa, Qb, P, out);
  k_noise<<<dim3(16777216/256), 256, 0, stream>>>(logn, out); // last: may overwrite scratch
}